// Round 22
// baseline (45792.932 us; speedup 1.0000x reference)
//
#include <hip/hip_runtime.h>
#include <hip/hip_bf16.h>
#include <stdint.h>

#define BATCH   256
#define T_STEPS 100
#define IN_DIM  700
#define H_DIM   1024
#define OUT_DIM 20

// Exactness contract (validated R21): per output element, cur = serial
// ascending fmaf chain in k, split into straight 512-chunks, each chunk's
// partial joined by one f32 add (first join exact from 0). LIF:
// rst=(m>thr)?thr:0; v=0.5f*m+cur; v-=rst; spk=(v>thr).
// K=700 panels [512,188]; K=1024 panels [512,512].

// ---------------- K0: layer-0 GEMM+LIF, all t in one launch ----------------
// block: 16 n x 64 b, 256 thr (4 waves). Wave w owns b in [16w,16w+16);
// lane (nl=ln&15, bq=ln>>4) owns b = 16w+bq+4j, j=0..3. m0 lives in regs.
__global__ __launch_bounds__(256) void k0_gemm_lif(
    const float* __restrict__ x,      // [256][100][700]
    const float* __restrict__ W0,     // [1024][700]
    const float* __restrict__ thr_p,
    uint16_t* __restrict__ spk0_bits) // [100][256][64] u16 words, bit i = n0+i
{
    __shared__ __align__(16) float Wt[16 * 708];   // stride 708: bank stagger
    __shared__ __align__(16) float At[64 * 132];   // stride 132

    const int tid = threadIdx.x;
    const int n0 = blockIdx.x * 16;
    const int b0 = blockIdx.y * 64;

    {   // W tile 16 x 700 (175 float4/row), 16 threads per row
        const int r = tid >> 4, c = tid & 15;
        const float* src = W0 + (size_t)(n0 + r) * IN_DIM;
        float* dst = Wt + r * 708;
        for (int f = c; f < 175; f += 16)
            ((float4*)dst)[f] = ((const float4*)src)[f];
    }
    __syncthreads();

    const int wv = tid >> 6, ln = tid & 63, nl = ln & 15, bq = ln >> 4;
    const float thr = *thr_p;
    float m[4] = {0.f, 0.f, 0.f, 0.f};

    for (int t = 0; t < T_STEPS; ++t) {
        float ps[4] = {0.f, 0.f, 0.f, 0.f};
        float s[4]  = {0.f, 0.f, 0.f, 0.f};
        for (int c = 0; c < 6; ++c) {          // 128-k chunks; join after c3 (512), c5 (700)
            __syncthreads();
            {   // stage A chunk: 64 rows x 128 k; 8 float4 per thread
                const int fbase = tid * 8;
#pragma unroll
                for (int u = 0; u < 8; ++u) {
                    const int fidx = fbase + u;
                    const int r = fidx >> 5, f = fidx & 31;
                    const int k = c * 128 + f * 4;
                    float4 v = make_float4(0.f, 0.f, 0.f, 0.f);
                    if (k + 3 < IN_DIM)
                        v = *(const float4*)(x + ((size_t)(b0 + r) * T_STEPS + t) * IN_DIM + k);
                    *(float4*)(At + r * 132 + f * 4) = v;
                }
            }
            __syncthreads();
            const int nk4 = (c == 5) ? 15 : 32;   // chunk 5 covers k in [640,700)
            const float* wrow = Wt + nl * 708 + c * 128;
            for (int k4 = 0; k4 < nk4; ++k4) {
                const float4 w4 = ((const float4*)wrow)[k4];
#pragma unroll
                for (int j = 0; j < 4; ++j) {
                    const int br = 16 * wv + bq + 4 * j;
                    const float4 a4 = *(const float4*)(At + br * 132 + k4 * 4);
                    ps[j] = __builtin_fmaf(a4.x, w4.x, ps[j]);
                    ps[j] = __builtin_fmaf(a4.y, w4.y, ps[j]);
                    ps[j] = __builtin_fmaf(a4.z, w4.z, ps[j]);
                    ps[j] = __builtin_fmaf(a4.w, w4.w, ps[j]);
                }
            }
            if (c == 3 || c == 5) {
#pragma unroll
                for (int j = 0; j < 4; ++j) { s[j] += ps[j]; ps[j] = 0.f; }
            }
        }
        float mn[4];
#pragma unroll
        for (int j = 0; j < 4; ++j) {
            const float rst = (m[j] > thr) ? thr : 0.f;
            float v = 0.5f * m[j] + s[j];
            v = v - rst;
            m[j] = v; mn[j] = v;
        }
#pragma unroll
        for (int j = 0; j < 4; ++j) {
            const unsigned long long mask = __ballot(mn[j] > thr);
            if (nl == 0) {
                const int br = 16 * wv + bq + 4 * j;
                spk0_bits[((size_t)t * BATCH + (b0 + br)) * 64 + blockIdx.x] =
                    (uint16_t)((mask >> (16 * bq)) & 0xFFFFull);
            }
        }
    }
}

// ---------------- K1: layer-1 GEMM+LIF, all t (A from spk0 bits) -----------
__global__ __launch_bounds__(256) void k1_gemm_lif(
    const uint16_t* __restrict__ spk0_bits,
    const float* __restrict__ W1,     // [1024][1024]
    const float* __restrict__ thr_p,
    uint16_t* __restrict__ spk1_bits)
{
    __shared__ __align__(16) float Wt[16 * 1028];
    __shared__ __align__(16) float At[64 * 132];

    const int tid = threadIdx.x;
    const int n0 = blockIdx.x * 16;
    const int b0 = blockIdx.y * 64;

    {   // W tile 16 x 1024 (256 f4/row)
        const int r = tid >> 4, c = tid & 15;
        const float* src = W1 + (size_t)(n0 + r) * H_DIM;
        float* dst = Wt + r * 1028;
        for (int f = c; f < 256; f += 16)
            ((float4*)dst)[f] = ((const float4*)src)[f];
    }
    __syncthreads();

    const int wv = tid >> 6, ln = tid & 63, nl = ln & 15, bq = ln >> 4;
    const float thr = *thr_p;
    float m[4] = {0.f, 0.f, 0.f, 0.f};

    for (int t = 0; t < T_STEPS; ++t) {
        float ps[4] = {0.f, 0.f, 0.f, 0.f};
        float s[4]  = {0.f, 0.f, 0.f, 0.f};
        for (int c = 0; c < 8; ++c) {          // joins after c3 (512) and c7 (1024)
            __syncthreads();
            {   // stage A chunk from bits: 512 u16 words, 2 per thread
#pragma unroll
                for (int u = 0; u < 2; ++u) {
                    const int widx = tid * 2 + u;
                    const int r = widx >> 3, wi = widx & 7;
                    const uint32_t w =
                        spk0_bits[((size_t)t * BATCH + (b0 + r)) * 64 + c * 8 + wi];
                    float* dst = At + r * 132 + wi * 16;
#pragma unroll
                    for (int i = 0; i < 16; ++i)
                        dst[i] = ((w >> i) & 1u) ? 1.0f : 0.0f;
                }
            }
            __syncthreads();
            const float* wrow = Wt + nl * 1028 + c * 128;
            for (int k4 = 0; k4 < 32; ++k4) {
                const float4 w4 = ((const float4*)wrow)[k4];
#pragma unroll
                for (int j = 0; j < 4; ++j) {
                    const int br = 16 * wv + bq + 4 * j;
                    const float4 a4 = *(const float4*)(At + br * 132 + k4 * 4);
                    ps[j] = __builtin_fmaf(a4.x, w4.x, ps[j]);
                    ps[j] = __builtin_fmaf(a4.y, w4.y, ps[j]);
                    ps[j] = __builtin_fmaf(a4.z, w4.z, ps[j]);
                    ps[j] = __builtin_fmaf(a4.w, w4.w, ps[j]);
                }
            }
            if (c == 3 || c == 7) {
#pragma unroll
                for (int j = 0; j < 4; ++j) { s[j] += ps[j]; ps[j] = 0.f; }
            }
        }
        float mn[4];
#pragma unroll
        for (int j = 0; j < 4; ++j) {
            const float rst = (m[j] > thr) ? thr : 0.f;
            float v = 0.5f * m[j] + s[j];
            v = v - rst;
            m[j] = v; mn[j] = v;
        }
#pragma unroll
        for (int j = 0; j < 4; ++j) {
            const unsigned long long mask = __ballot(mn[j] > thr);
            if (nl == 0) {
                const int br = 16 * wv + bq + 4 * j;
                spk1_bits[((size_t)t * BATCH + (b0 + br)) * 64 + blockIdx.x] =
                    (uint16_t)((mask >> (16 * bq)) & 0xFFFFull);
            }
        }
    }
}

// ---------------- K2a: output-layer currents for all t (parallel) ----------
// cur2[t,b,n] = exact BLIS dot(spk1[t,b,:], W2[n,:]).  bit? w : 0 adds are
// bit-exact vs fmaf(bit, w, ps): +0 adds are no-ops and ps is never -0.
__global__ __launch_bounds__(256) void k2a_gemm(
    const uint16_t* __restrict__ spk1_bits,
    const float* __restrict__ W2,     // [20][1024]
    float* __restrict__ cur2)         // [100*256][20]
{
    const int gid = blockIdx.x * 256 + threadIdx.x;
    const int q = gid / OUT_DIM, n = gid % OUT_DIM;
    if (q >= T_STEPS * BATCH) return;

    const uint16_t* bits = spk1_bits + (size_t)q * 64;
    const float* w = W2 + (size_t)n * H_DIM;
    float s = 0.f, ps = 0.f;
    for (int wi = 0; wi < 64; ++wi) {
        const uint32_t bw = bits[wi];
        const float4* w4p = (const float4*)(w + wi * 16);
#pragma unroll
        for (int f = 0; f < 4; ++f) {
            const float4 w4 = w4p[f];
            const int base = f * 4;
            ps += ((bw >> (base + 0)) & 1u) ? w4.x : 0.0f;
            ps += ((bw >> (base + 1)) & 1u) ? w4.y : 0.0f;
            ps += ((bw >> (base + 2)) & 1u) ? w4.z : 0.0f;
            ps += ((bw >> (base + 3)) & 1u) ? w4.w : 0.0f;
        }
        if (wi == 31) { s += ps; ps = 0.f; }   // panel join at k=512
    }
    s += ps;                                    // final join at k=1024
    cur2[(size_t)q * OUT_DIM + n] = s;
}

// ---------------- K2b: output-layer LIF recurrence + final writes ----------
__global__ __launch_bounds__(256) void k2b_lif_out(
    const float* __restrict__ cur2,
    const float* __restrict__ thr_p,
    float* __restrict__ out)           // [spk: 100*256*20][mem: 100*256*20]
{
    const int idx = blockIdx.x * 256 + threadIdx.x;
    if (idx >= BATCH * OUT_DIM) return;
    const float thr = *thr_p;
    const size_t stride = (size_t)BATCH * OUT_DIM;
    float m = 0.f;
    for (int t = 0; t < T_STEPS; ++t) {
        const float cur = cur2[(size_t)t * stride + idx];
        const float rst = (m > thr) ? thr : 0.f;
        float v = 0.5f * m + cur;
        v = v - rst;
        m = v;
        out[(size_t)t * stride + idx] = (v > thr) ? 1.0f : 0.0f;
        out[(size_t)T_STEPS * stride + (size_t)t * stride + idx] = v;
    }
}

extern "C" void kernel_launch(void* const* d_in, const int* in_sizes, int n_in,
                              void* d_out, int out_size, void* d_ws, size_t ws_size,
                              hipStream_t stream)
{
    const float* x    = (const float*)d_in[0];
    const float* W0   = (const float*)d_in[1];
    const float* W1   = (const float*)d_in[2];
    const float* W2   = (const float*)d_in[3];
    const float* thr0 = (const float*)d_in[4];
    const float* thr1 = (const float*)d_in[5];
    const float* thr2 = (const float*)d_in[6];

    // ws: spk0 bits 3.28 MB | spk1 bits 3.28 MB | cur2 2.05 MB  (= 8.6 MB)
    // every element written before read each call -> no memset needed
    uint16_t* spk0_bits = (uint16_t*)d_ws;
    uint16_t* spk1_bits = spk0_bits + (size_t)T_STEPS * BATCH * 64;
    float*    cur2      = (float*)(spk1_bits + (size_t)T_STEPS * BATCH * 64);

    k0_gemm_lif<<<dim3(H_DIM / 16, BATCH / 64), 256, 0, stream>>>(
        x, W0, thr0, spk0_bits);
    k1_gemm_lif<<<dim3(H_DIM / 16, BATCH / 64), 256, 0, stream>>>(
        spk0_bits, W1, thr1, spk1_bits);
    k2a_gemm<<<(T_STEPS * BATCH * OUT_DIM) / 256, 256, 0, stream>>>(
        spk1_bits, W2, cur2);
    k2b_lif_out<<<(BATCH * OUT_DIM + 255) / 256, 256, 0, stream>>>(
        cur2, thr2, (float*)d_out);
}